// Round 11
// baseline (167.055 us; speedup 1.0000x reference)
//
#include <hip/hip_runtime.h>
#include <hip/hip_bf16.h>
#include <cstdint>

#define NCLOUDS 16
#define N_PER   2048
#define KNN_K   16
#define CAP     48

typedef unsigned long long u64;
typedef __attribute__((ext_vector_type(16))) int si16;
#define INFF __builtin_inff()

// ---- cross-lane xor exchange: DPP for 1/2 (VALU pipe), ds_swizzle for
// 4/8/16 (DS pipe, no addr setup), shfl for 32. All exact xor exchanges. ----
template <int J>
__device__ __forceinline__ int ixor(int x) {
    if constexpr (J == 1)
        return __builtin_amdgcn_update_dpp(0, x, 0xB1, 0xF, 0xF, true);   // quad_perm [1,0,3,2]
    else if constexpr (J == 2)
        return __builtin_amdgcn_update_dpp(0, x, 0x4E, 0xF, 0xF, true);   // quad_perm [2,3,0,1]
    else if constexpr (J <= 16)
        return __builtin_amdgcn_ds_swizzle(x, (J << 10) | 0x1F);          // xor-J bitmode
    else
        return __shfl_xor(x, 32);
}
template <int J> __device__ __forceinline__ float fxor(float x) {
    return __int_as_float(ixor<J>(__float_as_int(x)));
}
template <int J> __device__ __forceinline__ u64 uxor(u64 x) {
    const int lo = ixor<J>((int)(x & 0xffffffffULL));
    const int hi = ixor<J>((int)(x >> 32));
    return ((u64)(unsigned)hi << 32) | (unsigned)lo;
}

// 16-lane-group max, all lanes receive result; pure VALU (DPP row ops).
__device__ __forceinline__ float dpp_max16(float x) {
    x = fmaxf(x, __int_as_float(__builtin_amdgcn_update_dpp(0, __float_as_int(x), 0xB1, 0xF, 0xF, true)));
    x = fmaxf(x, __int_as_float(__builtin_amdgcn_update_dpp(0, __float_as_int(x), 0x4E, 0xF, 0xF, true)));
    x = fmaxf(x, __int_as_float(__builtin_amdgcn_update_dpp(0, __float_as_int(x), 0x141, 0xF, 0xF, true))); // row_half_mirror
    x = fmaxf(x, __int_as_float(__builtin_amdgcn_update_dpp(0, __float_as_int(x), 0x140, 0xF, 0xF, true))); // row_mirror
    return x;
}

// ---------------------------------------------------------------------------
// KNN v10 (unchanged from R10, passed): 1024 blocks, 32 queries/block,
// 3 batched phases, DPP/swizzle bitonics, exact top_k tie order.
// ---------------------------------------------------------------------------
__global__ __launch_bounds__(512) void knn_kernel(const float* __restrict__ pos,
                                                  int* __restrict__ knn_out)
{
    __shared__ float qshare[3][32];
    __shared__ float smA[4][2][8][16];    // [pair][half][pair-local query][rank]
    __shared__ u64   buf[4][8][CAP];      // [pair][pair-local query][slot]
    __shared__ int   cnt[4][8];

    const int cloud = blockIdx.x >> 6;
    const int qblk  = blockIdx.x & 63;    // 64 qblocks/cloud, 32 queries each
    const int tid   = threadIdx.x;
    const int wave  = tid >> 6;
    const int lane  = tid & 63;
    const int H     = wave & 1;
    const int pr    = wave >> 1;

    const int b0 = cloud * N_PER;

    if (tid < 32) {
        const float* qp = pos + (size_t)(b0 + qblk * 32 + tid) * 3;
        qshare[0][tid] = qp[0];
        qshare[1][tid] = qp[1];
        qshare[2][tid] = qp[2];
        ((int*)cnt)[tid] = 0;
    }

    float cx[16], cy[16], cz[16], sc[16];
#pragma unroll
    for (int jj = 0; jj < 16; ++jj) {
        const int c = H * 1024 + jj * 64 + lane;
        const float* p = pos + (size_t)(b0 + c) * 3;
        cx[jj] = p[0]; cy[jj] = p[1]; cz[jj] = p[2];
        sc[jj] = fmaf(cz[jj], cz[jj], fmaf(cy[jj], cy[jj], cx[jj] * cx[jj]));
    }
    __syncthreads();

    // ================= phase 1: scan + sort lane-minima (ILP-2) ============
#pragma unroll 1
    for (int t = 0; t < 4; ++t) {
        const int qg0 = pr * 8 + 2 * t, qg1 = qg0 + 1;   // block-local query ids
        const float Q0x = qshare[0][qg0], Q0y = qshare[1][qg0], Q0z = qshare[2][qg0];
        const float Q1x = qshare[0][qg1], Q1y = qshare[1][qg1], Q1z = qshare[2][qg1];
        const float A0x = -2.0f * Q0x, A0y = -2.0f * Q0y, A0z = -2.0f * Q0z;
        const float A1x = -2.0f * Q1x, A1y = -2.0f * Q1y, A1z = -2.0f * Q1z;
        float v0 = INFF, v1 = INFF;
#pragma unroll
        for (int jj = 0; jj < 16; ++jj) {
            float e0 = fmaf(cx[jj], A0x, sc[jj]);
            float e1 = fmaf(cx[jj], A1x, sc[jj]);
            e0 = fmaf(cy[jj], A0y, e0);  e1 = fmaf(cy[jj], A1y, e1);
            e0 = fmaf(cz[jj], A0z, e0);  e1 = fmaf(cz[jj], A1z, e1);
            v0 = fminf(v0, e0);          v1 = fminf(v1, e1);
        }
        // bitonic ascending sort of 64 lane minima (both chains)
#define FS(K, J) { const float o0 = fxor<J>(v0), o1 = fxor<J>(v1);              \
                   const bool km = (((lane & J) == 0) == ((lane & K) == 0));    \
                   v0 = km ? fminf(v0, o0) : fmaxf(v0, o0);                     \
                   v1 = km ? fminf(v1, o1) : fmaxf(v1, o1); }
        FS(2,1)
        FS(4,2) FS(4,1)
        FS(8,4) FS(8,2) FS(8,1)
        FS(16,8) FS(16,4) FS(16,2) FS(16,1)
        FS(32,16) FS(32,8) FS(32,4) FS(32,2) FS(32,1)
        FS(64,32) FS(64,16) FS(64,8) FS(64,4) FS(64,2) FS(64,1)
#undef FS
        if (lane < 16) {
            smA[pr][H][2 * t][lane]     = v0;   // pair-local index
            smA[pr][H][2 * t + 1][lane] = v1;
        }
    }
    __syncthreads();

    // ================= phase 2: merge threshold + collect (ILP-2) ==========
#pragma unroll 1
    for (int t = 0; t < 4; ++t) {
        const int q0 = 2 * t, q1 = q0 + 1;           // pair-local query ids
        // union-16th of the two sorted 16-lists: min_i max(A[i-1], B[15-i])
        float a0 = -INFF, a1 = -INFF, b0v = -INFF, b1v = -INFF;
        if (lane > 0 && lane <= 16) {
            a0 = smA[pr][0][q0][lane - 1];
            a1 = smA[pr][0][q1][lane - 1];
        }
        if (lane < 16) {
            b0v = smA[pr][1][q0][15 - lane];
            b1v = smA[pr][1][q1][15 - lane];
        }
        float m0 = (lane <= 16) ? fmaxf(a0, b0v) : INFF;
        float m1 = (lane <= 16) ? fmaxf(a1, b1v) : INFF;
        m0 = fminf(m0, fxor<1>(m0));   m1 = fminf(m1, fxor<1>(m1));
        m0 = fminf(m0, fxor<2>(m0));   m1 = fminf(m1, fxor<2>(m1));
        m0 = fminf(m0, fxor<4>(m0));   m1 = fminf(m1, fxor<4>(m1));
        m0 = fminf(m0, fxor<8>(m0));   m1 = fminf(m1, fxor<8>(m1));
        m0 = fminf(m0, fxor<16>(m0));  m1 = fminf(m1, fxor<16>(m1));
        m0 = fminf(m0, fxor<32>(m0));  m1 = fminf(m1, fxor<32>(m1));

        const int qg0 = pr * 8 + q0, qg1 = pr * 8 + q1;
        const float Q0x = qshare[0][qg0], Q0y = qshare[1][qg0], Q0z = qshare[2][qg0];
        const float Q1x = qshare[0][qg1], Q1y = qshare[1][qg1], Q1z = qshare[2][qg1];
        const float qq0 = fmaf(Q0z, Q0z, fmaf(Q0y, Q0y, Q0x * Q0x));
        const float qq1 = fmaf(Q1z, Q1z, fmaf(Q1y, Q1y, Q1x * Q1x));
        const float T0 = (m0 + qq0) * (1.0f + 1e-5f) + 1e-4f;
        const float T1 = (m1 + qq1) * (1.0f + 1e-5f) + 1e-4f;

        // exact d2 (reference association), collect <= T
#pragma unroll
        for (int jj = 0; jj < 16; ++jj) {
            const int c = H * 1024 + jj * 64 + lane;
            const float dx0 = __fsub_rn(Q0x, cx[jj]);
            const float dy0 = __fsub_rn(Q0y, cy[jj]);
            const float dz0 = __fsub_rn(Q0z, cz[jj]);
            const float d20 = __fadd_rn(__fadd_rn(__fmul_rn(dx0, dx0), __fmul_rn(dy0, dy0)),
                                        __fmul_rn(dz0, dz0));
            if (d20 <= T0) {
                const int slot = atomicAdd(&cnt[pr][q0], 1);
                if (slot < CAP)
                    buf[pr][q0][slot] = ((u64)__float_as_uint(d20) << 32) | (unsigned)c;
            }
            const float dx1 = __fsub_rn(Q1x, cx[jj]);
            const float dy1 = __fsub_rn(Q1y, cy[jj]);
            const float dz1 = __fsub_rn(Q1z, cz[jj]);
            const float d21 = __fadd_rn(__fadd_rn(__fmul_rn(dx1, dx1), __fmul_rn(dy1, dy1)),
                                        __fmul_rn(dz1, dz1));
            if (d21 <= T1) {
                const int slot = atomicAdd(&cnt[pr][q1], 1);
                if (slot < CAP)
                    buf[pr][q1][slot] = ((u64)__float_as_uint(d21) << 32) | (unsigned)c;
            }
        }
    }
    __syncthreads();

    // ================= phase 3: select top-16 (ILP-2, 2 iters/wave) ========
#pragma unroll 1
    for (int s = 0; s < 2; ++s) {
        const int q0 = H * 4 + 2 * s, q1 = q0 + 1;   // wave's select queries
        const int n0 = min(cnt[pr][q0], CAP);
        const int n1 = min(cnt[pr][q1], CAP);
        u64 k0 = (lane < n0) ? buf[pr][q0][lane] : ~0ULL;
        u64 k1 = (lane < n1) ? buf[pr][q1][lane] : ~0ULL;
#define US(K, J) { const u64 o0 = uxor<J>(k0), o1 = uxor<J>(k1);                \
                   const bool km = (((lane & J) == 0) == ((lane & K) == 0));    \
                   const u64 l0 = k0 < o0 ? k0 : o0, h0 = k0 < o0 ? o0 : k0;    \
                   k0 = km ? l0 : h0;                                           \
                   const u64 l1 = k1 < o1 ? k1 : o1, h1 = k1 < o1 ? o1 : k1;    \
                   k1 = km ? l1 : h1; }
        US(2,1)
        US(4,2) US(4,1)
        US(8,4) US(8,2) US(8,1)
        US(16,8) US(16,4) US(16,2) US(16,1)
        US(32,16) US(32,8) US(32,4) US(32,2) US(32,1)
        US(64,32) US(64,16) US(64,8) US(64,4) US(64,2) US(64,1)
#undef US
        if (lane < KNN_K) {
            knn_out[((size_t)b0 + qblk * 32 + pr * 8 + q0) * KNN_K + lane] =
                b0 + (int)(unsigned)(k0 & 0xffffffffu);
            knn_out[((size_t)b0 + qblk * 32 + pr * 8 + q1) * KNN_K + lane] =
                b0 + (int)(unsigned)(k1 & 0xffffffffu);
        }
    }
}

// ---------------------------------------------------------------------------
// Per-point pre-projection: w[p] = ba + hin[p]@Wa_h + pos[p]@Wa_s,
// v[p] = pos[p]@Wa_s. (x@Wa with x=concat(h_j, p_j-p_i) == w[j] - v[i].)
// ---------------------------------------------------------------------------
template <int CH>
__global__ __launch_bounds__(256) void pre_kernel(
    const float* __restrict__ pos, const float* __restrict__ hin,
    const float* __restrict__ Wa, const float* __restrict__ ba,
    float* __restrict__ w, float* __restrict__ v)
{
    const int gth = blockIdx.x * 256 + threadIdx.x;
    const int p   = gth >> 3;
    const int i8  = gth & 7;
    const float4* Wa4 = (const float4*)Wa;
    const float4* ba4 = (const float4*)ba;

    float4 acc = ba4[i8];
    const float* hrow = hin + (size_t)p * CH;
#pragma unroll
    for (int d = 0; d < CH; ++d) {
        const float h = hrow[d];
        const float4 wr = Wa4[d * 8 + i8];
        acc.x = fmaf(h, wr.x, acc.x);
        acc.y = fmaf(h, wr.y, acc.y);
        acc.z = fmaf(h, wr.z, acc.z);
        acc.w = fmaf(h, wr.w, acc.w);
    }
    float4 vs = make_float4(0.f, 0.f, 0.f, 0.f);
    const float* prow = pos + (size_t)p * 3;
#pragma unroll
    for (int d = 0; d < 3; ++d) {
        const float pd = prow[d];
        const float4 wr = Wa4[(CH + d) * 8 + i8];
        vs.x = fmaf(pd, wr.x, vs.x);
        vs.y = fmaf(pd, wr.y, vs.y);
        vs.z = fmaf(pd, wr.z, vs.z);
        vs.w = fmaf(pd, wr.w, vs.w);
    }
    ((float4*)w)[(size_t)p * 8 + i8] =
        make_float4(acc.x + vs.x, acc.y + vs.y, acc.z + vs.z, acc.w + vs.w);
    ((float4*)v)[(size_t)p * 8 + i8] = vs;
}

// ---------------------------------------------------------------------------
// Edge-MLP layer: lane = edge (p,k); hid = relu(w[j]-v[p]); o[32] register
// accumulator. Wb rows + bb are loaded via inline-asm s_load_dwordx16 at
// wave-uniform addresses -> guaranteed SCALAR pipe (the R10 source relied on
// LLVM scalarizing `Wb[c*32+c2]`; if it emitted per-lane global_load
// broadcasts instead, that's ~8K VMEM instrs per CU-resident-set ≈ the
// missing ~30us/layer). fma takes the SGPR operand directly (1 SGPR legal).
// Max over the 16 edge-lanes via DPP (VALU pipe).
// ---------------------------------------------------------------------------
__global__ __launch_bounds__(256) void layer_kernel(
    const int*   __restrict__ knn,
    const float* __restrict__ Wb, const float* __restrict__ bb,
    const float* __restrict__ w,  const float* __restrict__ v,
    float* __restrict__ hout)
{
    const int gth = blockIdx.x * 256 + threadIdx.x;
    const int p = gth >> 4;
    const int k = gth & 15;
    const int j = knn[gth];

    const float4* w4 = (const float4*)w;
    const float4* v4 = (const float4*)v;

    float hid[32];
#pragma unroll
    for (int i = 0; i < 8; ++i) {
        const float4 a = w4[(size_t)j * 8 + i];
        const float4 b = v4[(size_t)p * 8 + i];
        hid[4 * i + 0] = fmaxf(a.x - b.x, 0.0f);
        hid[4 * i + 1] = fmaxf(a.y - b.y, 0.0f);
        hid[4 * i + 2] = fmaxf(a.z - b.z, 0.0f);
        hid[4 * i + 3] = fmaxf(a.w - b.w, 0.0f);
    }

    float o[32];
    {   // o init = bb, via scalar load
        si16 ba_, bbv;
        asm volatile("s_load_dwordx16 %0, %2, 0x0\n\t"
                     "s_load_dwordx16 %1, %2, 0x40\n\t"
                     "s_waitcnt lgkmcnt(0)"
                     : "=s"(ba_), "=s"(bbv) : "s"(bb));
#pragma unroll
        for (int c2 = 0; c2 < 16; ++c2) o[c2] = __int_as_float(ba_[c2]);
#pragma unroll
        for (int c2 = 0; c2 < 16; ++c2) o[16 + c2] = __int_as_float(bbv[c2]);
    }

#pragma unroll
    for (int c = 0; c < 32; ++c) {
        const float hc = hid[c];
        si16 ra, rb;   // Wb row c: 32 floats, wave-uniform -> scalar pipe
        asm volatile("s_load_dwordx16 %0, %2, 0x0\n\t"
                     "s_load_dwordx16 %1, %2, 0x40\n\t"
                     "s_waitcnt lgkmcnt(0)"
                     : "=s"(ra), "=s"(rb) : "s"(Wb + c * 32));
#pragma unroll
        for (int c2 = 0; c2 < 16; ++c2)
            o[c2] = fmaf(hc, __int_as_float(ra[c2]), o[c2]);
#pragma unroll
        for (int c2 = 0; c2 < 16; ++c2)
            o[16 + c2] = fmaf(hc, __int_as_float(rb[c2]), o[16 + c2]);
    }

    float out0 = 0.0f, out1 = 0.0f;
#pragma unroll
    for (int c2 = 0; c2 < 32; ++c2) {
        const float s = dpp_max16(o[c2]);
        if ((c2 & 15) == k) { if (c2 < 16) out0 = s; else out1 = s; }
    }
    hout[(size_t)p * 32 + k]      = fmaxf(out0, 0.0f);
    hout[(size_t)p * 32 + 16 + k] = fmaxf(out1, 0.0f);
}

// ---------------------------------------------------------------------------
// Global max pool over each cloud + linear classifier. 1 block per cloud.
// ---------------------------------------------------------------------------
__global__ __launch_bounds__(256) void pool_kernel(
    const float* __restrict__ h2, const float* __restrict__ Wc,
    const float* __restrict__ bc, float* __restrict__ out)
{
    __shared__ float red[8][32];
    __shared__ float sg[32];
    const int cloud = blockIdx.x;
    const int t = threadIdx.x;
    const int c = t & 31, row = t >> 5;
    float m = 0.0f;  // h2 >= 0 after relu
    for (int p = row; p < N_PER; p += 8)
        m = fmaxf(m, h2[((size_t)cloud * N_PER + p) * 32 + c]);
    red[row][c] = m;
    __syncthreads();
    if (t < 32) {
        float gv = red[0][t];
#pragma unroll
        for (int r = 1; r < 8; ++r) gv = fmaxf(gv, red[r][t]);
        sg[t] = gv;
    }
    __syncthreads();
    if (t < 10) {
        float s = bc[t];
#pragma unroll
        for (int c0 = 0; c0 < 32; ++c0) s = fmaf(sg[c0], Wc[c0 * 10 + t], s);
        out[cloud * 10 + t] = s;
    }
}

extern "C" void kernel_launch(void* const* d_in, const int* in_sizes, int n_in,
                              void* d_out, int out_size, void* d_ws, size_t ws_size,
                              hipStream_t stream)
{
    const float* pos = (const float*)d_in[0];
    const float* W1a = (const float*)d_in[2];
    const float* b1a = (const float*)d_in[3];
    const float* W1b = (const float*)d_in[4];
    const float* b1b = (const float*)d_in[5];
    const float* W2a = (const float*)d_in[6];
    const float* b2a = (const float*)d_in[7];
    const float* W2b = (const float*)d_in[8];
    const float* b2b = (const float*)d_in[9];
    const float* Wc  = (const float*)d_in[10];
    const float* bc  = (const float*)d_in[11];

    int*   knn = (int*)d_ws;                                   // 2 MB
    float* w   = (float*)((char*)d_ws + (size_t)(2  << 20));   // 4 MB
    float* v   = (float*)((char*)d_ws + (size_t)(6  << 20));   // 4 MB
    float* h1  = (float*)((char*)d_ws + (size_t)(10 << 20));   // 4 MB
    float* h2  = h1;   // h1 dead after pre2; layer2 reads only w,v
    float* out = (float*)d_out;

    const int npts = NCLOUDS * N_PER;

    knn_kernel<<<dim3(NCLOUDS * 64), dim3(512), 0, stream>>>(pos, knn);
    pre_kernel<3><<<dim3(npts * 8 / 256), dim3(256), 0, stream>>>(
        pos, pos, W1a, b1a, w, v);
    layer_kernel<<<dim3(npts * KNN_K / 256), dim3(256), 0, stream>>>(
        knn, W1b, b1b, w, v, h1);
    pre_kernel<32><<<dim3(npts * 8 / 256), dim3(256), 0, stream>>>(
        pos, h1, W2a, b2a, w, v);
    layer_kernel<<<dim3(npts * KNN_K / 256), dim3(256), 0, stream>>>(
        knn, W2b, b2b, w, v, h2);
    pool_kernel<<<dim3(NCLOUDS), dim3(256), 0, stream>>>(h2, Wc, bc, out);
}

// Round 12
// 151.062 us; speedup vs baseline: 1.1059x; 1.1059x over previous
//
#include <hip/hip_runtime.h>
#include <hip/hip_bf16.h>
#include <cstdint>

#define NCLOUDS 16
#define N_PER   2048
#define KNN_K   16
#define CAP     48

typedef unsigned long long u64;
#define INFF __builtin_inff()

// ---- cross-lane xor exchange: DPP for 1/2 (VALU pipe), ds_swizzle for
// 4/8/16 (DS pipe, no addr setup), shfl for 32. All exact xor exchanges. ----
template <int J>
__device__ __forceinline__ int ixor(int x) {
    if constexpr (J == 1)
        return __builtin_amdgcn_update_dpp(0, x, 0xB1, 0xF, 0xF, true);   // quad_perm [1,0,3,2]
    else if constexpr (J == 2)
        return __builtin_amdgcn_update_dpp(0, x, 0x4E, 0xF, 0xF, true);   // quad_perm [2,3,0,1]
    else if constexpr (J <= 16)
        return __builtin_amdgcn_ds_swizzle(x, (J << 10) | 0x1F);          // xor-J bitmode
    else
        return __shfl_xor(x, 32);
}
template <int J> __device__ __forceinline__ float fxor(float x) {
    return __int_as_float(ixor<J>(__float_as_int(x)));
}
template <int J> __device__ __forceinline__ u64 uxor(u64 x) {
    const int lo = ixor<J>((int)(x & 0xffffffffULL));
    const int hi = ixor<J>((int)(x >> 32));
    return ((u64)(unsigned)hi << 32) | (unsigned)lo;
}

// 16-lane-group max, all lanes receive result; pure VALU (DPP row ops).
__device__ __forceinline__ float dpp_max16(float x) {
    x = fmaxf(x, __int_as_float(__builtin_amdgcn_update_dpp(0, __float_as_int(x), 0xB1, 0xF, 0xF, true)));
    x = fmaxf(x, __int_as_float(__builtin_amdgcn_update_dpp(0, __float_as_int(x), 0x4E, 0xF, 0xF, true)));
    x = fmaxf(x, __int_as_float(__builtin_amdgcn_update_dpp(0, __float_as_int(x), 0x141, 0xF, 0xF, true))); // row_half_mirror
    x = fmaxf(x, __int_as_float(__builtin_amdgcn_update_dpp(0, __float_as_int(x), 0x140, 0xF, 0xF, true))); // row_mirror
    return x;
}

// ---------------------------------------------------------------------------
// KNN v11 = v10 (passed, 56us) + fused pre1 epilogue: the block's 32 queries
// are exactly its owned points; w1[p] = b1a + pos[p]@W1a[0:3] + pos[p]@W1a[3:6],
// v1[p] = pos[p]@W1a[3:6]. ~20 FMA/thread, no barrier needed (pos+weights
// only). Removes the pre1 kernel launch.
// ---------------------------------------------------------------------------
__global__ __launch_bounds__(512) void knn_kernel(const float* __restrict__ pos,
                                                  int* __restrict__ knn_out,
                                                  const float* __restrict__ W1a,
                                                  const float* __restrict__ b1a,
                                                  float* __restrict__ w1,
                                                  float* __restrict__ v1)
{
    __shared__ float qshare[3][32];
    __shared__ float smA[4][2][8][16];    // [pair][half][pair-local query][rank]
    __shared__ u64   buf[4][8][CAP];      // [pair][pair-local query][slot]
    __shared__ int   cnt[4][8];

    const int cloud = blockIdx.x >> 6;
    const int qblk  = blockIdx.x & 63;    // 64 qblocks/cloud, 32 queries each
    const int tid   = threadIdx.x;
    const int wave  = tid >> 6;
    const int lane  = tid & 63;
    const int H     = wave & 1;
    const int pr    = wave >> 1;

    const int b0 = cloud * N_PER;

    if (tid < 32) {
        const float* qp = pos + (size_t)(b0 + qblk * 32 + tid) * 3;
        qshare[0][tid] = qp[0];
        qshare[1][tid] = qp[1];
        qshare[2][tid] = qp[2];
        ((int*)cnt)[tid] = 0;
    }

    float cx[16], cy[16], cz[16], sc[16];
#pragma unroll
    for (int jj = 0; jj < 16; ++jj) {
        const int c = H * 1024 + jj * 64 + lane;
        const float* p = pos + (size_t)(b0 + c) * 3;
        cx[jj] = p[0]; cy[jj] = p[1]; cz[jj] = p[2];
        sc[jj] = fmaf(cz[jj], cz[jj], fmaf(cy[jj], cy[jj], cx[jj] * cx[jj]));
    }
    __syncthreads();

    // ================= phase 1: scan + sort lane-minima (ILP-2) ============
#pragma unroll 1
    for (int t = 0; t < 4; ++t) {
        const int qg0 = pr * 8 + 2 * t, qg1 = qg0 + 1;   // block-local query ids
        const float Q0x = qshare[0][qg0], Q0y = qshare[1][qg0], Q0z = qshare[2][qg0];
        const float Q1x = qshare[0][qg1], Q1y = qshare[1][qg1], Q1z = qshare[2][qg1];
        const float A0x = -2.0f * Q0x, A0y = -2.0f * Q0y, A0z = -2.0f * Q0z;
        const float A1x = -2.0f * Q1x, A1y = -2.0f * Q1y, A1z = -2.0f * Q1z;
        float v0 = INFF, v1r = INFF;
#pragma unroll
        for (int jj = 0; jj < 16; ++jj) {
            float e0 = fmaf(cx[jj], A0x, sc[jj]);
            float e1 = fmaf(cx[jj], A1x, sc[jj]);
            e0 = fmaf(cy[jj], A0y, e0);  e1 = fmaf(cy[jj], A1y, e1);
            e0 = fmaf(cz[jj], A0z, e0);  e1 = fmaf(cz[jj], A1z, e1);
            v0 = fminf(v0, e0);          v1r = fminf(v1r, e1);
        }
        // bitonic ascending sort of 64 lane minima (both chains)
#define FS(K, J) { const float o0 = fxor<J>(v0), o1 = fxor<J>(v1r);             \
                   const bool km = (((lane & J) == 0) == ((lane & K) == 0));    \
                   v0 = km ? fminf(v0, o0) : fmaxf(v0, o0);                     \
                   v1r = km ? fminf(v1r, o1) : fmaxf(v1r, o1); }
        FS(2,1)
        FS(4,2) FS(4,1)
        FS(8,4) FS(8,2) FS(8,1)
        FS(16,8) FS(16,4) FS(16,2) FS(16,1)
        FS(32,16) FS(32,8) FS(32,4) FS(32,2) FS(32,1)
        FS(64,32) FS(64,16) FS(64,8) FS(64,4) FS(64,2) FS(64,1)
#undef FS
        if (lane < 16) {
            smA[pr][H][2 * t][lane]     = v0;   // pair-local index
            smA[pr][H][2 * t + 1][lane] = v1r;
        }
    }
    __syncthreads();

    // ================= phase 2: merge threshold + collect (ILP-2) ==========
#pragma unroll 1
    for (int t = 0; t < 4; ++t) {
        const int q0 = 2 * t, q1 = q0 + 1;           // pair-local query ids
        // union-16th of the two sorted 16-lists: min_i max(A[i-1], B[15-i])
        float a0 = -INFF, a1 = -INFF, b0v = -INFF, b1v = -INFF;
        if (lane > 0 && lane <= 16) {
            a0 = smA[pr][0][q0][lane - 1];
            a1 = smA[pr][0][q1][lane - 1];
        }
        if (lane < 16) {
            b0v = smA[pr][1][q0][15 - lane];
            b1v = smA[pr][1][q1][15 - lane];
        }
        float m0 = (lane <= 16) ? fmaxf(a0, b0v) : INFF;
        float m1 = (lane <= 16) ? fmaxf(a1, b1v) : INFF;
        m0 = fminf(m0, fxor<1>(m0));   m1 = fminf(m1, fxor<1>(m1));
        m0 = fminf(m0, fxor<2>(m0));   m1 = fminf(m1, fxor<2>(m1));
        m0 = fminf(m0, fxor<4>(m0));   m1 = fminf(m1, fxor<4>(m1));
        m0 = fminf(m0, fxor<8>(m0));   m1 = fminf(m1, fxor<8>(m1));
        m0 = fminf(m0, fxor<16>(m0));  m1 = fminf(m1, fxor<16>(m1));
        m0 = fminf(m0, fxor<32>(m0));  m1 = fminf(m1, fxor<32>(m1));

        const int qg0 = pr * 8 + q0, qg1 = pr * 8 + q1;
        const float Q0x = qshare[0][qg0], Q0y = qshare[1][qg0], Q0z = qshare[2][qg0];
        const float Q1x = qshare[0][qg1], Q1y = qshare[1][qg1], Q1z = qshare[2][qg1];
        const float qq0 = fmaf(Q0z, Q0z, fmaf(Q0y, Q0y, Q0x * Q0x));
        const float qq1 = fmaf(Q1z, Q1z, fmaf(Q1y, Q1y, Q1x * Q1x));
        const float T0 = (m0 + qq0) * (1.0f + 1e-5f) + 1e-4f;
        const float T1 = (m1 + qq1) * (1.0f + 1e-5f) + 1e-4f;

        // exact d2 (reference association), collect <= T
#pragma unroll
        for (int jj = 0; jj < 16; ++jj) {
            const int c = H * 1024 + jj * 64 + lane;
            const float dx0 = __fsub_rn(Q0x, cx[jj]);
            const float dy0 = __fsub_rn(Q0y, cy[jj]);
            const float dz0 = __fsub_rn(Q0z, cz[jj]);
            const float d20 = __fadd_rn(__fadd_rn(__fmul_rn(dx0, dx0), __fmul_rn(dy0, dy0)),
                                        __fmul_rn(dz0, dz0));
            if (d20 <= T0) {
                const int slot = atomicAdd(&cnt[pr][q0], 1);
                if (slot < CAP)
                    buf[pr][q0][slot] = ((u64)__float_as_uint(d20) << 32) | (unsigned)c;
            }
            const float dx1 = __fsub_rn(Q1x, cx[jj]);
            const float dy1 = __fsub_rn(Q1y, cy[jj]);
            const float dz1 = __fsub_rn(Q1z, cz[jj]);
            const float d21 = __fadd_rn(__fadd_rn(__fmul_rn(dx1, dx1), __fmul_rn(dy1, dy1)),
                                        __fmul_rn(dz1, dz1));
            if (d21 <= T1) {
                const int slot = atomicAdd(&cnt[pr][q1], 1);
                if (slot < CAP)
                    buf[pr][q1][slot] = ((u64)__float_as_uint(d21) << 32) | (unsigned)c;
            }
        }
    }
    __syncthreads();

    // ================= phase 3: select top-16 (ILP-2, 2 iters/wave) ========
#pragma unroll 1
    for (int s = 0; s < 2; ++s) {
        const int q0 = H * 4 + 2 * s, q1 = q0 + 1;   // wave's select queries
        const int n0 = min(cnt[pr][q0], CAP);
        const int n1 = min(cnt[pr][q1], CAP);
        u64 k0 = (lane < n0) ? buf[pr][q0][lane] : ~0ULL;
        u64 k1 = (lane < n1) ? buf[pr][q1][lane] : ~0ULL;
#define US(K, J) { const u64 o0 = uxor<J>(k0), o1 = uxor<J>(k1);                \
                   const bool km = (((lane & J) == 0) == ((lane & K) == 0));    \
                   const u64 l0 = k0 < o0 ? k0 : o0, h0 = k0 < o0 ? o0 : k0;    \
                   k0 = km ? l0 : h0;                                           \
                   const u64 l1 = k1 < o1 ? k1 : o1, h1 = k1 < o1 ? o1 : k1;    \
                   k1 = km ? l1 : h1; }
        US(2,1)
        US(4,2) US(4,1)
        US(8,4) US(8,2) US(8,1)
        US(16,8) US(16,4) US(16,2) US(16,1)
        US(32,16) US(32,8) US(32,4) US(32,2) US(32,1)
        US(64,32) US(64,16) US(64,8) US(64,4) US(64,2) US(64,1)
#undef US
        if (lane < KNN_K) {
            knn_out[((size_t)b0 + qblk * 32 + pr * 8 + q0) * KNN_K + lane] =
                b0 + (int)(unsigned)(k0 & 0xffffffffu);
            knn_out[((size_t)b0 + qblk * 32 + pr * 8 + q1) * KNN_K + lane] =
                b0 + (int)(unsigned)(k1 & 0xffffffffu);
        }
    }

    // ================= fused pre1 epilogue (this block's 32 points) ========
    {
        const int pt = tid >> 4;            // 0..31
        const int kk = tid & 15;
        const int gp = b0 + qblk * 32 + pt;
        const float p0 = pos[3 * (size_t)gp + 0];
        const float p1 = pos[3 * (size_t)gp + 1];
        const float p2 = pos[3 * (size_t)gp + 2];
        float vA = 0.f, vB = 0.f;
        float wA = b1a[kk], wB = b1a[16 + kk];
#pragma unroll
        for (int d = 0; d < 3; ++d) {
            const float pd = d == 0 ? p0 : (d == 1 ? p1 : p2);
            wA = fmaf(pd, W1a[d * 32 + kk],        wA);
            wB = fmaf(pd, W1a[d * 32 + 16 + kk],   wB);
            vA = fmaf(pd, W1a[(3 + d) * 32 + kk],      vA);
            vB = fmaf(pd, W1a[(3 + d) * 32 + 16 + kk], vB);
        }
        w1[(size_t)gp * 32 + kk]      = wA + vA;
        w1[(size_t)gp * 32 + 16 + kk] = wB + vB;
        v1[(size_t)gp * 32 + kk]      = vA;
        v1[(size_t)gp * 32 + 16 + kk] = vB;
    }
}

// ---------------------------------------------------------------------------
// Edge-MLP layer: lane = edge (p,k); hid = relu(w[j]-v[p]); o[32] register
// accumulator (Wb rows contiguous wave-uniform); DPP max over 16 edge-lanes.
// FUSE_PRE2: h1 stays in LDS (never global); epilogue computes next layer's
// per-point pre-projection w2 = b2a + h1@W2a_h + pos@W2a_s, v2 = pos@W2a_s.
// Otherwise writes h rows to outA.
// ---------------------------------------------------------------------------
template <bool FUSE_PRE2>
__global__ __launch_bounds__(256) void layer_kernel(
    const int*   __restrict__ knn,
    const float* __restrict__ Wb, const float* __restrict__ bb,
    const float* __restrict__ w,  const float* __restrict__ v,
    const float* __restrict__ pos,
    const float* __restrict__ Wna, const float* __restrict__ bna,
    float* __restrict__ outA, float* __restrict__ outB)
{
    __shared__ float h1s[16][32];   // used only when FUSE_PRE2

    const int gth = blockIdx.x * 256 + threadIdx.x;
    const int p = gth >> 4;
    const int k = gth & 15;
    const int j = knn[gth];

    const float4* w4 = (const float4*)w;
    const float4* v4 = (const float4*)v;

    float hid[32];
#pragma unroll
    for (int i = 0; i < 8; ++i) {
        const float4 a = w4[(size_t)j * 8 + i];
        const float4 b = v4[(size_t)p * 8 + i];
        hid[4 * i + 0] = fmaxf(a.x - b.x, 0.0f);
        hid[4 * i + 1] = fmaxf(a.y - b.y, 0.0f);
        hid[4 * i + 2] = fmaxf(a.z - b.z, 0.0f);
        hid[4 * i + 3] = fmaxf(a.w - b.w, 0.0f);
    }

    float o[32];
#pragma unroll
    for (int c2 = 0; c2 < 32; ++c2) o[c2] = bb[c2];
#pragma unroll
    for (int c = 0; c < 32; ++c) {
        const float hc = hid[c];
        const float* row = Wb + c * 32;   // contiguous, wave-uniform
#pragma unroll
        for (int c2 = 0; c2 < 32; ++c2) o[c2] = fmaf(hc, row[c2], o[c2]);
    }

    float out0 = 0.0f, out1 = 0.0f;
#pragma unroll
    for (int c2 = 0; c2 < 32; ++c2) {
        const float s = dpp_max16(o[c2]);
        if ((c2 & 15) == k) { if (c2 < 16) out0 = s; else out1 = s; }
    }
    out0 = fmaxf(out0, 0.0f);   // outer relu
    out1 = fmaxf(out1, 0.0f);

    if constexpr (!FUSE_PRE2) {
        outA[(size_t)p * 32 + k]      = out0;
        outA[(size_t)p * 32 + 16 + k] = out1;
    } else {
        const int pl = threadIdx.x >> 4;   // local point 0..15
        h1s[pl][k]      = out0;
        h1s[pl][16 + k] = out1;
        __syncthreads();
        // pre2: thread (pl,k) computes channels k and k+16 of w2,v2
        float accA = bna[k], accB = bna[16 + k];
#pragma unroll
        for (int c = 0; c < 32; ++c) {
            const float hc = h1s[pl][c];
            accA = fmaf(hc, Wna[c * 32 + k],      accA);
            accB = fmaf(hc, Wna[c * 32 + 16 + k], accB);
        }
        float vA = 0.f, vB = 0.f;
#pragma unroll
        for (int d = 0; d < 3; ++d) {
            const float pd = pos[3 * (size_t)p + d];
            vA = fmaf(pd, Wna[(32 + d) * 32 + k],      vA);
            vB = fmaf(pd, Wna[(32 + d) * 32 + 16 + k], vB);
        }
        outA[(size_t)p * 32 + k]      = accA + vA;
        outA[(size_t)p * 32 + 16 + k] = accB + vB;
        outB[(size_t)p * 32 + k]      = vA;
        outB[(size_t)p * 32 + 16 + k] = vB;
    }
}

// ---------------------------------------------------------------------------
// Global max pool over each cloud + linear classifier. 1 block per cloud.
// ---------------------------------------------------------------------------
__global__ __launch_bounds__(256) void pool_kernel(
    const float* __restrict__ h2, const float* __restrict__ Wc,
    const float* __restrict__ bc, float* __restrict__ out)
{
    __shared__ float red[8][32];
    __shared__ float sg[32];
    const int cloud = blockIdx.x;
    const int t = threadIdx.x;
    const int c = t & 31, row = t >> 5;
    float m = 0.0f;  // h2 >= 0 after relu
    for (int p = row; p < N_PER; p += 8)
        m = fmaxf(m, h2[((size_t)cloud * N_PER + p) * 32 + c]);
    red[row][c] = m;
    __syncthreads();
    if (t < 32) {
        float gv = red[0][t];
#pragma unroll
        for (int r = 1; r < 8; ++r) gv = fmaxf(gv, red[r][t]);
        sg[t] = gv;
    }
    __syncthreads();
    if (t < 10) {
        float s = bc[t];
#pragma unroll
        for (int c0 = 0; c0 < 32; ++c0) s = fmaf(sg[c0], Wc[c0 * 10 + t], s);
        out[cloud * 10 + t] = s;
    }
}

extern "C" void kernel_launch(void* const* d_in, const int* in_sizes, int n_in,
                              void* d_out, int out_size, void* d_ws, size_t ws_size,
                              hipStream_t stream)
{
    const float* pos = (const float*)d_in[0];
    const float* W1a = (const float*)d_in[2];
    const float* b1a = (const float*)d_in[3];
    const float* W1b = (const float*)d_in[4];
    const float* b1b = (const float*)d_in[5];
    const float* W2a = (const float*)d_in[6];
    const float* b2a = (const float*)d_in[7];
    const float* W2b = (const float*)d_in[8];
    const float* b2b = (const float*)d_in[9];
    const float* Wc  = (const float*)d_in[10];
    const float* bc  = (const float*)d_in[11];

    int*   knn = (int*)d_ws;                                   // 2 MB
    float* w1  = (float*)((char*)d_ws + (size_t)(2  << 20));   // 4 MB
    float* v1  = (float*)((char*)d_ws + (size_t)(6  << 20));   // 4 MB
    float* w2  = (float*)((char*)d_ws + (size_t)(10 << 20));   // 4 MB
    float* v2  = (float*)((char*)d_ws + (size_t)(14 << 20));   // 4 MB
    float* h2  = (float*)((char*)d_ws + (size_t)(18 << 20));   // 4 MB
    float* out = (float*)d_out;

    const int npts = NCLOUDS * N_PER;

    knn_kernel<<<dim3(NCLOUDS * 64), dim3(512), 0, stream>>>(
        pos, knn, W1a, b1a, w1, v1);
    layer_kernel<true><<<dim3(npts * KNN_K / 256), dim3(256), 0, stream>>>(
        knn, W1b, b1b, w1, v1, pos, W2a, b2a, w2, v2);
    layer_kernel<false><<<dim3(npts * KNN_K / 256), dim3(256), 0, stream>>>(
        knn, W2b, b2b, w2, v2, pos, W2a, b2a, h2, nullptr);
    pool_kernel<<<dim3(NCLOUDS), dim3(256), 0, stream>>>(h2, Wc, bc, out);
}

// Round 13
// 138.704 us; speedup vs baseline: 1.2044x; 1.0891x over previous
//
#include <hip/hip_runtime.h>
#include <hip/hip_bf16.h>
#include <cstdint>

#define NCLOUDS 16
#define N_PER   2048
#define KNN_K   16
#define CAP     48

typedef unsigned long long u64;
#define INFF __builtin_inff()

// ---- cross-lane xor exchange: DPP for 1/2 (VALU pipe), ds_swizzle for
// 4/8/16 (DS pipe, no addr setup), shfl for 32. All exact xor exchanges. ----
template <int J>
__device__ __forceinline__ int ixor(int x) {
    if constexpr (J == 1)
        return __builtin_amdgcn_update_dpp(0, x, 0xB1, 0xF, 0xF, true);   // quad_perm [1,0,3,2]
    else if constexpr (J == 2)
        return __builtin_amdgcn_update_dpp(0, x, 0x4E, 0xF, 0xF, true);   // quad_perm [2,3,0,1]
    else if constexpr (J <= 16)
        return __builtin_amdgcn_ds_swizzle(x, (J << 10) | 0x1F);          // xor-J bitmode
    else
        return __shfl_xor(x, 32);
}
template <int J> __device__ __forceinline__ float fxor(float x) {
    return __int_as_float(ixor<J>(__float_as_int(x)));
}
template <int J> __device__ __forceinline__ u64 uxor(u64 x) {
    const int lo = ixor<J>((int)(x & 0xffffffffULL));
    const int hi = ixor<J>((int)(x >> 32));
    return ((u64)(unsigned)hi << 32) | (unsigned)lo;
}

// 16-lane-group max, all lanes receive result; pure VALU (DPP row ops).
__device__ __forceinline__ float dpp_max16(float x) {
    x = fmaxf(x, __int_as_float(__builtin_amdgcn_update_dpp(0, __float_as_int(x), 0xB1, 0xF, 0xF, true)));
    x = fmaxf(x, __int_as_float(__builtin_amdgcn_update_dpp(0, __float_as_int(x), 0x4E, 0xF, 0xF, true)));
    x = fmaxf(x, __int_as_float(__builtin_amdgcn_update_dpp(0, __float_as_int(x), 0x141, 0xF, 0xF, true))); // row_half_mirror
    x = fmaxf(x, __int_as_float(__builtin_amdgcn_update_dpp(0, __float_as_int(x), 0x140, 0xF, 0xF, true))); // row_mirror
    return x;
}

// ---------------------------------------------------------------------------
// KNN v11 (R12, passed): v10 + fused pre1 epilogue; also zeroes gbuf/counter
// for the fused pool (graph-replay safe: re-zeroed every call).
// ---------------------------------------------------------------------------
__global__ __launch_bounds__(512) void knn_kernel(const float* __restrict__ pos,
                                                  int* __restrict__ knn_out,
                                                  const float* __restrict__ W1a,
                                                  const float* __restrict__ b1a,
                                                  float* __restrict__ w1,
                                                  float* __restrict__ v1,
                                                  float* __restrict__ gbuf,
                                                  int* __restrict__ counter)
{
    __shared__ float qshare[3][32];
    __shared__ float smA[4][2][8][16];    // [pair][half][pair-local query][rank]
    __shared__ u64   buf[4][8][CAP];      // [pair][pair-local query][slot]
    __shared__ int   cnt[4][8];

    const int cloud = blockIdx.x >> 6;
    const int qblk  = blockIdx.x & 63;    // 64 qblocks/cloud, 32 queries each
    const int tid   = threadIdx.x;
    const int wave  = tid >> 6;
    const int lane  = tid & 63;
    const int H     = wave & 1;
    const int pr    = wave >> 1;

    const int b0 = cloud * N_PER;

    if (blockIdx.x == 0) {                // init fused-pool accumulators
        if (tid < NCLOUDS * 32) gbuf[tid] = 0.0f;
        if (tid == 0) *counter = 0;
    }

    if (tid < 32) {
        const float* qp = pos + (size_t)(b0 + qblk * 32 + tid) * 3;
        qshare[0][tid] = qp[0];
        qshare[1][tid] = qp[1];
        qshare[2][tid] = qp[2];
        ((int*)cnt)[tid] = 0;
    }

    float cx[16], cy[16], cz[16], sc[16];
#pragma unroll
    for (int jj = 0; jj < 16; ++jj) {
        const int c = H * 1024 + jj * 64 + lane;
        const float* p = pos + (size_t)(b0 + c) * 3;
        cx[jj] = p[0]; cy[jj] = p[1]; cz[jj] = p[2];
        sc[jj] = fmaf(cz[jj], cz[jj], fmaf(cy[jj], cy[jj], cx[jj] * cx[jj]));
    }
    __syncthreads();

    // ================= phase 1: scan + sort lane-minima (ILP-2) ============
#pragma unroll 1
    for (int t = 0; t < 4; ++t) {
        const int qg0 = pr * 8 + 2 * t, qg1 = qg0 + 1;   // block-local query ids
        const float Q0x = qshare[0][qg0], Q0y = qshare[1][qg0], Q0z = qshare[2][qg0];
        const float Q1x = qshare[0][qg1], Q1y = qshare[1][qg1], Q1z = qshare[2][qg1];
        const float A0x = -2.0f * Q0x, A0y = -2.0f * Q0y, A0z = -2.0f * Q0z;
        const float A1x = -2.0f * Q1x, A1y = -2.0f * Q1y, A1z = -2.0f * Q1z;
        float v0 = INFF, v1r = INFF;
#pragma unroll
        for (int jj = 0; jj < 16; ++jj) {
            float e0 = fmaf(cx[jj], A0x, sc[jj]);
            float e1 = fmaf(cx[jj], A1x, sc[jj]);
            e0 = fmaf(cy[jj], A0y, e0);  e1 = fmaf(cy[jj], A1y, e1);
            e0 = fmaf(cz[jj], A0z, e0);  e1 = fmaf(cz[jj], A1z, e1);
            v0 = fminf(v0, e0);          v1r = fminf(v1r, e1);
        }
        // bitonic ascending sort of 64 lane minima (both chains)
#define FS(K, J) { const float o0 = fxor<J>(v0), o1 = fxor<J>(v1r);             \
                   const bool km = (((lane & J) == 0) == ((lane & K) == 0));    \
                   v0 = km ? fminf(v0, o0) : fmaxf(v0, o0);                     \
                   v1r = km ? fminf(v1r, o1) : fmaxf(v1r, o1); }
        FS(2,1)
        FS(4,2) FS(4,1)
        FS(8,4) FS(8,2) FS(8,1)
        FS(16,8) FS(16,4) FS(16,2) FS(16,1)
        FS(32,16) FS(32,8) FS(32,4) FS(32,2) FS(32,1)
        FS(64,32) FS(64,16) FS(64,8) FS(64,4) FS(64,2) FS(64,1)
#undef FS
        if (lane < 16) {
            smA[pr][H][2 * t][lane]     = v0;   // pair-local index
            smA[pr][H][2 * t + 1][lane] = v1r;
        }
    }
    __syncthreads();

    // ================= phase 2: merge threshold + collect (ILP-2) ==========
#pragma unroll 1
    for (int t = 0; t < 4; ++t) {
        const int q0 = 2 * t, q1 = q0 + 1;           // pair-local query ids
        // union-16th of the two sorted 16-lists: min_i max(A[i-1], B[15-i])
        float a0 = -INFF, a1 = -INFF, b0v = -INFF, b1v = -INFF;
        if (lane > 0 && lane <= 16) {
            a0 = smA[pr][0][q0][lane - 1];
            a1 = smA[pr][0][q1][lane - 1];
        }
        if (lane < 16) {
            b0v = smA[pr][1][q0][15 - lane];
            b1v = smA[pr][1][q1][15 - lane];
        }
        float m0 = (lane <= 16) ? fmaxf(a0, b0v) : INFF;
        float m1 = (lane <= 16) ? fmaxf(a1, b1v) : INFF;
        m0 = fminf(m0, fxor<1>(m0));   m1 = fminf(m1, fxor<1>(m1));
        m0 = fminf(m0, fxor<2>(m0));   m1 = fminf(m1, fxor<2>(m1));
        m0 = fminf(m0, fxor<4>(m0));   m1 = fminf(m1, fxor<4>(m1));
        m0 = fminf(m0, fxor<8>(m0));   m1 = fminf(m1, fxor<8>(m1));
        m0 = fminf(m0, fxor<16>(m0));  m1 = fminf(m1, fxor<16>(m1));
        m0 = fminf(m0, fxor<32>(m0));  m1 = fminf(m1, fxor<32>(m1));

        const int qg0 = pr * 8 + q0, qg1 = pr * 8 + q1;
        const float Q0x = qshare[0][qg0], Q0y = qshare[1][qg0], Q0z = qshare[2][qg0];
        const float Q1x = qshare[0][qg1], Q1y = qshare[1][qg1], Q1z = qshare[2][qg1];
        const float qq0 = fmaf(Q0z, Q0z, fmaf(Q0y, Q0y, Q0x * Q0x));
        const float qq1 = fmaf(Q1z, Q1z, fmaf(Q1y, Q1y, Q1x * Q1x));
        const float T0 = (m0 + qq0) * (1.0f + 1e-5f) + 1e-4f;
        const float T1 = (m1 + qq1) * (1.0f + 1e-5f) + 1e-4f;

        // exact d2 (reference association), collect <= T
#pragma unroll
        for (int jj = 0; jj < 16; ++jj) {
            const int c = H * 1024 + jj * 64 + lane;
            const float dx0 = __fsub_rn(Q0x, cx[jj]);
            const float dy0 = __fsub_rn(Q0y, cy[jj]);
            const float dz0 = __fsub_rn(Q0z, cz[jj]);
            const float d20 = __fadd_rn(__fadd_rn(__fmul_rn(dx0, dx0), __fmul_rn(dy0, dy0)),
                                        __fmul_rn(dz0, dz0));
            if (d20 <= T0) {
                const int slot = atomicAdd(&cnt[pr][q0], 1);
                if (slot < CAP)
                    buf[pr][q0][slot] = ((u64)__float_as_uint(d20) << 32) | (unsigned)c;
            }
            const float dx1 = __fsub_rn(Q1x, cx[jj]);
            const float dy1 = __fsub_rn(Q1y, cy[jj]);
            const float dz1 = __fsub_rn(Q1z, cz[jj]);
            const float d21 = __fadd_rn(__fadd_rn(__fmul_rn(dx1, dx1), __fmul_rn(dy1, dy1)),
                                        __fmul_rn(dz1, dz1));
            if (d21 <= T1) {
                const int slot = atomicAdd(&cnt[pr][q1], 1);
                if (slot < CAP)
                    buf[pr][q1][slot] = ((u64)__float_as_uint(d21) << 32) | (unsigned)c;
            }
        }
    }
    __syncthreads();

    // ================= phase 3: select top-16 (ILP-2, 2 iters/wave) ========
#pragma unroll 1
    for (int s = 0; s < 2; ++s) {
        const int q0 = H * 4 + 2 * s, q1 = q0 + 1;   // wave's select queries
        const int n0 = min(cnt[pr][q0], CAP);
        const int n1 = min(cnt[pr][q1], CAP);
        u64 k0 = (lane < n0) ? buf[pr][q0][lane] : ~0ULL;
        u64 k1 = (lane < n1) ? buf[pr][q1][lane] : ~0ULL;
#define US(K, J) { const u64 o0 = uxor<J>(k0), o1 = uxor<J>(k1);                \
                   const bool km = (((lane & J) == 0) == ((lane & K) == 0));    \
                   const u64 l0 = k0 < o0 ? k0 : o0, h0 = k0 < o0 ? o0 : k0;    \
                   k0 = km ? l0 : h0;                                           \
                   const u64 l1 = k1 < o1 ? k1 : o1, h1 = k1 < o1 ? o1 : k1;    \
                   k1 = km ? l1 : h1; }
        US(2,1)
        US(4,2) US(4,1)
        US(8,4) US(8,2) US(8,1)
        US(16,8) US(16,4) US(16,2) US(16,1)
        US(32,16) US(32,8) US(32,4) US(32,2) US(32,1)
        US(64,32) US(64,16) US(64,8) US(64,4) US(64,2) US(64,1)
#undef US
        if (lane < KNN_K) {
            knn_out[((size_t)b0 + qblk * 32 + pr * 8 + q0) * KNN_K + lane] =
                b0 + (int)(unsigned)(k0 & 0xffffffffu);
            knn_out[((size_t)b0 + qblk * 32 + pr * 8 + q1) * KNN_K + lane] =
                b0 + (int)(unsigned)(k1 & 0xffffffffu);
        }
    }

    // ================= fused pre1 epilogue (this block's 32 points) ========
    {
        const int pt = tid >> 4;            // 0..31
        const int kk = tid & 15;
        const int gp = b0 + qblk * 32 + pt;
        const float p0 = pos[3 * (size_t)gp + 0];
        const float p1 = pos[3 * (size_t)gp + 1];
        const float p2 = pos[3 * (size_t)gp + 2];
        float vA = 0.f, vB = 0.f;
        float wA = b1a[kk], wB = b1a[16 + kk];
#pragma unroll
        for (int d = 0; d < 3; ++d) {
            const float pd = d == 0 ? p0 : (d == 1 ? p1 : p2);
            wA = fmaf(pd, W1a[d * 32 + kk],        wA);
            wB = fmaf(pd, W1a[d * 32 + 16 + kk],   wB);
            vA = fmaf(pd, W1a[(3 + d) * 32 + kk],      vA);
            vB = fmaf(pd, W1a[(3 + d) * 32 + 16 + kk], vB);
        }
        w1[(size_t)gp * 32 + kk]      = wA + vA;
        w1[(size_t)gp * 32 + 16 + kk] = wB + vB;
        v1[(size_t)gp * 32 + kk]      = vA;
        v1[(size_t)gp * 32 + 16 + kk] = vB;
    }
}

// ---------------------------------------------------------------------------
// Edge-MLP layer, coalesced-gather version. Block = 256 thr = 16 points.
// Stage the 256 needed w-rows into LDS with 8-lanes-per-row cooperative loads
// (each dwordx4 instr covers 8 CONTIGUOUS 128B rows vs 64 scattered lines in
// the naive per-edge gather). Rows at stride 36 floats (16B-aligned, bank-
// rotated). Lane then reads its own row via ds_read_b128.
// MODE 1: epilogue computes next layer's pre-projection (w2,v2); h1 never
//         touches global.
// MODE 2: fused global-max-pool (block max -> 32 float-bit atomicMax) +
//         last-block classifier. h2 never touches global; pool kernel gone.
// ---------------------------------------------------------------------------
template <int MODE>
__global__ __launch_bounds__(256) void layer_kernel(
    const int*   __restrict__ knn,
    const float* __restrict__ Wb, const float* __restrict__ bb,
    const float* __restrict__ w,  const float* __restrict__ v,
    const float* __restrict__ pos,
    const float* __restrict__ Wna, const float* __restrict__ bna,
    float* __restrict__ outA, float* __restrict__ outB,
    const float* __restrict__ Wc, const float* __restrict__ bc,
    float* __restrict__ gbuf, int* __restrict__ counter,
    float* __restrict__ out)
{
    __shared__ float wst[256 * 36];   // staged rows; later reused as scratch
    __shared__ float vst[16 * 36];
    __shared__ int   jl[256];
    __shared__ int   lastFlag;

    const int tid = threadIdx.x;
    const int gth = blockIdx.x * 256 + tid;
    const int P0  = blockIdx.x * 16;            // first point of block

    jl[tid] = knn[gth];
    __syncthreads();

    // ---- stage w rows (256 x 32 floats), 8 lanes per row ----
#pragma unroll
    for (int s = 0; s < 8; ++s) {
        const int r = s * 32 + (tid >> 3);
        const int i = tid & 7;
        const float4 t4 = *(const float4*)(w + (size_t)jl[r] * 32 + i * 4);
        *(float4*)&wst[r * 36 + i * 4] = t4;
    }
    // ---- stage v rows (16 x 32 floats), fully coalesced ----
    if (tid < 128) {
        const int r = tid >> 3, i = tid & 7;
        const float4 t4 = *(const float4*)(v + (size_t)(P0 + r) * 32 + i * 4);
        *(float4*)&vst[r * 36 + i * 4] = t4;
    }
    __syncthreads();

    const int k  = tid & 15;
    const int pl = tid >> 4;

    float hid[32];
#pragma unroll
    for (int i = 0; i < 8; ++i) {
        const float4 a = *(const float4*)&wst[tid * 36 + i * 4];
        const float4 b = *(const float4*)&vst[pl  * 36 + i * 4];
        hid[4 * i + 0] = fmaxf(a.x - b.x, 0.0f);
        hid[4 * i + 1] = fmaxf(a.y - b.y, 0.0f);
        hid[4 * i + 2] = fmaxf(a.z - b.z, 0.0f);
        hid[4 * i + 3] = fmaxf(a.w - b.w, 0.0f);
    }

    float o[32];
#pragma unroll
    for (int c2 = 0; c2 < 32; ++c2) o[c2] = bb[c2];
#pragma unroll
    for (int c = 0; c < 32; ++c) {
        const float hc = hid[c];
        const float* row = Wb + c * 32;   // contiguous, wave-uniform
#pragma unroll
        for (int c2 = 0; c2 < 32; ++c2) o[c2] = fmaf(hc, row[c2], o[c2]);
    }

    float out0 = 0.0f, out1 = 0.0f;
#pragma unroll
    for (int c2 = 0; c2 < 32; ++c2) {
        const float s = dpp_max16(o[c2]);
        if ((c2 & 15) == k) { if (c2 < 16) out0 = s; else out1 = s; }
    }
    out0 = fmaxf(out0, 0.0f);   // outer relu
    out1 = fmaxf(out1, 0.0f);

    __syncthreads();            // wst reads done; reuse wst as scratch
    float* hs = wst;            // [16][32] current-layer h rows
    hs[pl * 32 + k]      = out0;
    hs[pl * 32 + 16 + k] = out1;
    __syncthreads();

    if constexpr (MODE == 1) {
        // pre2: thread (pl,k) computes channels k and k+16 of w2,v2
        const int p = gth >> 4;   // global point id
        float accA = bna[k], accB = bna[16 + k];
#pragma unroll
        for (int c = 0; c < 32; ++c) {
            const float hc = hs[pl * 32 + c];
            accA = fmaf(hc, Wna[c * 32 + k],      accA);
            accB = fmaf(hc, Wna[c * 32 + 16 + k], accB);
        }
        float vA = 0.f, vB = 0.f;
#pragma unroll
        for (int d = 0; d < 3; ++d) {
            const float pd = pos[3 * (size_t)p + d];
            vA = fmaf(pd, Wna[(32 + d) * 32 + k],      vA);
            vB = fmaf(pd, Wna[(32 + d) * 32 + 16 + k], vB);
        }
        outA[(size_t)p * 32 + k]      = accA + vA;
        outA[(size_t)p * 32 + 16 + k] = accB + vB;
        outB[(size_t)p * 32 + k]      = vA;
        outB[(size_t)p * 32 + 16 + k] = vB;
    } else {
        // fused pool: block-local max over 16 points, then device atomicMax
        if (tid < 32) {
            float m = hs[tid];
#pragma unroll
            for (int p2 = 1; p2 < 16; ++p2) m = fmaxf(m, hs[p2 * 32 + tid]);
            const int cloud = P0 >> 11;     // 2048 points per cloud
            atomicMax((int*)&gbuf[cloud * 32 + tid], __float_as_int(m));
        }
        __syncthreads();                    // drains the atomics (vmcnt)
        if (tid == 0) {
            __threadfence();
            lastFlag = (atomicAdd(counter, 1) == (int)gridDim.x - 1);
        }
        __syncthreads();
        if (lastFlag) {
            float* gl = wst;                // reuse scratch
            for (int t = tid; t < NCLOUDS * 32; t += 256)
                gl[t] = __int_as_float(atomicMax((int*)&gbuf[t], 0)); // coherent read
            __syncthreads();
            if (tid < NCLOUDS * 10) {
                const int cl = tid / 10, cls = tid - cl * 10;
                float s2 = bc[cls];
#pragma unroll
                for (int c = 0; c < 32; ++c)
                    s2 = fmaf(gl[cl * 32 + c], Wc[c * 10 + cls], s2);
                out[tid] = s2;
            }
        }
    }
}

extern "C" void kernel_launch(void* const* d_in, const int* in_sizes, int n_in,
                              void* d_out, int out_size, void* d_ws, size_t ws_size,
                              hipStream_t stream)
{
    const float* pos = (const float*)d_in[0];
    const float* W1a = (const float*)d_in[2];
    const float* b1a = (const float*)d_in[3];
    const float* W1b = (const float*)d_in[4];
    const float* b1b = (const float*)d_in[5];
    const float* W2a = (const float*)d_in[6];
    const float* b2a = (const float*)d_in[7];
    const float* W2b = (const float*)d_in[8];
    const float* b2b = (const float*)d_in[9];
    const float* Wc  = (const float*)d_in[10];
    const float* bc  = (const float*)d_in[11];

    int*   knn     = (int*)d_ws;                                   // 2 MB
    float* w1      = (float*)((char*)d_ws + (size_t)(2  << 20));   // 4 MB
    float* v1      = (float*)((char*)d_ws + (size_t)(6  << 20));   // 4 MB
    float* w2      = (float*)((char*)d_ws + (size_t)(10 << 20));   // 4 MB
    float* v2      = (float*)((char*)d_ws + (size_t)(14 << 20));   // 4 MB
    float* gbuf    = (float*)((char*)d_ws + (size_t)(18 << 20));   // 2 KB
    int*   counter = (int*)((char*)d_ws + (size_t)(18 << 20) + 4096);
    float* out     = (float*)d_out;

    const int npts = NCLOUDS * N_PER;

    knn_kernel<<<dim3(NCLOUDS * 64), dim3(512), 0, stream>>>(
        pos, knn, W1a, b1a, w1, v1, gbuf, counter);
    layer_kernel<1><<<dim3(npts * KNN_K / 256), dim3(256), 0, stream>>>(
        knn, W1b, b1b, w1, v1, pos, W2a, b2a, w2, v2,
        nullptr, nullptr, nullptr, nullptr, nullptr);
    layer_kernel<2><<<dim3(npts * KNN_K / 256), dim3(256), 0, stream>>>(
        knn, W2b, b2b, w2, v2, pos, nullptr, nullptr, nullptr, nullptr,
        Wc, bc, gbuf, counter, out);
}